// Round 14
// baseline (352.858 us; speedup 1.0000x reference)
//
#include <hip/hip_runtime.h>
#include <hip/hip_fp16.h>
#include <math.h>

#define U_NUM_ 50000
#define I_NUM_ 50000
#define EMBED_ 64
#define ATT_   64
#define NNZ_   2500000
#define NBKT_  1024
#define BROWS_ 49           // rows per bucket: 1024*49 = 50176 >= 50000

// ---------------------------------------------------------------------------
// Pass 0: four 50000x64 @ 64x64^T projections, fp32 accumulate, fp16 store,
// interleaved so one row fetch serves both directions:
//   utab[row][  0: 64] = Qu   utab[row][ 64:128] = Ku
//   itab[col][  0: 64] = Ki   itab[col][ 64:128] = Qi
// ---------------------------------------------------------------------------
__global__ __launch_bounds__(256) void proj_kernel(
        const float* __restrict__ user_embed, const float* __restrict__ item_embed,
        const float* __restrict__ Wq, const float* __restrict__ bq,
        const float* __restrict__ Wk, const float* __restrict__ bk,
        __half* __restrict__ utab, __half* __restrict__ itab) {
    __shared__ float Wl[ATT_][EMBED_ + 1];
    __shared__ float El[32][EMBED_];
    __shared__ float bl[ATT_];

    const int combo = blockIdx.y;
    const float* E = (combo == 0 || combo == 3) ? user_embed : item_embed;
    const float* W = (combo == 0 || combo == 2) ? Wq : Wk;
    const float* b = (combo == 0 || combo == 2) ? bq : bk;
    __half* tab    = (combo == 0 || combo == 3) ? utab : itab;
    const int off  = (combo == 0 || combo == 1) ? 0 : 64;

    const int tid = threadIdx.x;

    for (int i4 = tid; i4 < 1024; i4 += 256) {
        const int r = i4 >> 4, c4 = (i4 & 15) * 4;
        float4 w = ((const float4*)W)[i4];
        Wl[r][c4 + 0] = w.x; Wl[r][c4 + 1] = w.y;
        Wl[r][c4 + 2] = w.z; Wl[r][c4 + 3] = w.w;
    }
    if (tid < ATT_) bl[tid] = b[tid];

    const int row0 = blockIdx.x * 32;
    for (int i4 = tid; i4 < 512; i4 += 256) {
        const int r = i4 >> 4, c4 = (i4 & 15) * 4;
        const int gr = row0 + r;
        float4 ev = make_float4(0.f, 0.f, 0.f, 0.f);
        if (gr < U_NUM_) ev = ((const float4*)(E + (size_t)gr * EMBED_))[i4 & 15];
        *(float4*)&El[r][c4] = ev;
    }
    __syncthreads();

    const int a  = tid & 63;
    const int rw = tid >> 6;
    float acc[8];
    #pragma unroll
    for (int k = 0; k < 8; ++k) acc[k] = bl[a];

    #pragma unroll 2
    for (int e4 = 0; e4 < 16; ++e4) {
        const float w0 = Wl[a][e4 * 4 + 0];
        const float w1 = Wl[a][e4 * 4 + 1];
        const float w2 = Wl[a][e4 * 4 + 2];
        const float w3 = Wl[a][e4 * 4 + 3];
        #pragma unroll
        for (int k = 0; k < 8; ++k) {
            float4 ev = *(const float4*)&El[rw + 4 * k][e4 * 4];
            acc[k] = fmaf(ev.x, w0, fmaf(ev.y, w1, fmaf(ev.z, w2, fmaf(ev.w, w3, acc[k]))));
        }
    }

    #pragma unroll
    for (int k = 0; k < 8; ++k) {
        const int gr = row0 + rw + 4 * k;
        if (gr < U_NUM_) tab[(size_t)gr * 128 + off + a] = __float2half(acc[k]);
    }
}

// ---------------------------------------------------------------------------
// Sort 1: per-row-bucket counts (1024 LDS bins, 1024 global atomics / block).
// ---------------------------------------------------------------------------
__global__ __launch_bounds__(256) void count_kernel(
        const int* __restrict__ rows, unsigned* __restrict__ gcnt) {
    __shared__ unsigned cl[NBKT_];
    for (int i = threadIdx.x; i < NBKT_; i += 256) cl[i] = 0;
    __syncthreads();
    int j = blockIdx.x * blockDim.x + threadIdx.x;
    const int st = gridDim.x * blockDim.x;
    for (; j < NNZ_; j += st) atomicAdd(&cl[rows[j] / BROWS_], 1u);
    __syncthreads();
    for (int i = threadIdx.x; i < NBKT_; i += 256)
        if (cl[i]) atomicAdd(&gcnt[i], cl[i]);
}

// ---------------------------------------------------------------------------
// Sort 2: parallel exclusive scan over 1024 counts (Hillis-Steele in LDS).
// ---------------------------------------------------------------------------
__global__ __launch_bounds__(1024) void scan_kernel(
        const unsigned* __restrict__ gcnt,
        unsigned* __restrict__ gbase, unsigned* __restrict__ gcursor) {
    __shared__ unsigned part[NBKT_];
    const int t = threadIdx.x;
    part[t] = gcnt[t];
    __syncthreads();
    #pragma unroll
    for (int off = 1; off < NBKT_; off <<= 1) {
        unsigned v = (t >= off) ? part[t - off] : 0u;
        __syncthreads();
        part[t] += v;
        __syncthreads();
    }
    const unsigned ex = (t == 0) ? 0u : part[t - 1];   // exclusive prefix
    gbase[t] = ex;
    gcursor[t] = ex;
    if (t == NBKT_ - 1) gbase[NBKT_] = part[t];
}

// ---------------------------------------------------------------------------
// Sort 3: scatter edges into bucket-major records. Block reserves per-bucket
// ranges once -> rec writes form contiguous runs.
// Record = {(r<<16)|c, j, u_ui, u_iu}.
// ---------------------------------------------------------------------------
__global__ __launch_bounds__(256) void scatter_kernel(
        const int* __restrict__ rows, const int* __restrict__ cols,
        const float* __restrict__ u_ui, const float* __restrict__ u_iu,
        unsigned* __restrict__ gcursor, uint4* __restrict__ recs) {
    __shared__ unsigned cnt[NBKT_];
    __shared__ unsigned base[NBKT_];
    const int tid = threadIdx.x;
    const int chunk = (NNZ_ + gridDim.x - 1) / gridDim.x;
    const int j0 = blockIdx.x * chunk;
    const int j1 = min(j0 + chunk, NNZ_);
    for (int i = tid; i < NBKT_; i += 256) cnt[i] = 0;
    __syncthreads();
    for (int j = j0 + tid; j < j1; j += 256)
        atomicAdd(&cnt[rows[j] / BROWS_], 1u);
    __syncthreads();
    for (int i = tid; i < NBKT_; i += 256) {
        base[i] = atomicAdd(&gcursor[i], cnt[i]);
        cnt[i] = 0;
    }
    __syncthreads();
    for (int j = j0 + tid; j < j1; j += 256) {
        const int r = rows[j];
        const int b = r / BROWS_;
        const unsigned pos = base[b] + atomicAdd(&cnt[b], 1u);
        uint4 rec;
        rec.x = ((unsigned)r << 16) | (unsigned)cols[j];
        rec.y = (unsigned)j;
        rec.z = __float_as_uint(u_ui[j]);
        rec.w = __float_as_uint(u_iu[j]);
        recs[pos] = rec;
    }
}

// ---------------------------------------------------------------------------
// LDS-staged gather v6: FOUR 256-thread blocks per bucket (grid 4096 = 2x
// device block capacity -> real backfill; R12/R13 grids exactly equalled
// capacity, so bucket imbalance idled CUs, occupancy 44%).
//  - utab slice (12.25 KB) staged in LDS (each block stages it; 50 MB total
//    streamed, ~8 us).
//  - 8x unroll: 8 in-flight 16 B itab fetches per thread.
//  - ui row sums in LDS, flushed with per-block global atomicAdd (49/block).
//  - e-values written straight to out[] (proven time-neutral vs alternatives).
// Max-subtraction skipped (v analytically bounded <= ~31, exp fits f32).
// ---------------------------------------------------------------------------
__global__ __launch_bounds__(256) void gather_kernel(
        const unsigned* __restrict__ gbase, const uint4* __restrict__ recs,
        const __half* __restrict__ utab, const __half* __restrict__ itab,
        float* __restrict__ out, float* __restrict__ segsum) {
    __shared__ uint4 uslice[BROWS_ * 16];            // 49 rows x 256 B = 12544 B
    __shared__ float rowsum[BROWS_];
    const int b    = blockIdx.x >> 2;                // bucket
    const int part = blockIdx.x & 3;                 // quarter
    const int tid  = threadIdx.x;
    const int lane = tid & 15;
    const int grp  = tid >> 4;                       // 0..15

    const uint4* up = (const uint4*)utab;
    const uint4* ip = (const uint4*)itab;

    const int r0g   = b * BROWS_;
    const int nrow  = max(0, min(BROWS_, U_NUM_ - r0g));
    for (int i = tid; i < nrow * 16; i += 256)
        uslice[i] = up[(size_t)r0g * 16 + i];
    for (int i = tid; i < BROWS_; i += 256) rowsum[i] = 0.f;
    __syncthreads();

    // this block's quarter of the bucket's record range
    const int bs = (int)gbase[b], be = (int)gbase[b + 1];
    const int len = be - bs;
    const int s = bs + (int)(((long long)len * part) >> 2);
    const int e = bs + (int)(((long long)len * (part + 1)) >> 2);

    const int nq = (e - s + 7) >> 3;
    const bool iu = (lane & 8) != 0;
    union H8 { uint4 u; __half2 h[4]; };

    for (int q = grp; q < nq; q += 16) {
        const int base = s + q * 8;
        const int nv = min(8, e - base);
        uint4 R[8];
        H8 ib[8];
        #pragma unroll
        for (int t = 0; t < 8; ++t) {
            R[t] = recs[(t < nv) ? (base + t) : base];
            ib[t].u = ip[(size_t)(R[t].x & 0xffff) * 16 + lane];  // 8 in flight
        }
        #pragma unroll
        for (int t = 0; t < 8; ++t) {
            H8 ul; ul.u = uslice[((int)(R[t].x >> 16) - r0g) * 16 + lane];
            float p = 0.f;
            #pragma unroll
            for (int m = 0; m < 4; ++m) {
                float2 x = __half22float2(ul.h[m]);
                float2 y = __half22float2(ib[t].h[m]);
                p = fmaf(x.x, y.x, p); p = fmaf(x.y, y.y, p);
            }
            p += __shfl_xor(p, 1);
            p += __shfl_xor(p, 2);
            p += __shfl_xor(p, 4);
            const float n  = __uint_as_float(iu ? R[t].w : R[t].z);
            const float ev = __expf(p - __logf(-__logf(n)));   // TAU = 1
            const int r = (int)(R[t].x >> 16), c = (int)(R[t].x & 0xffff);
            const int j = (int)R[t].y;
            if (t < nv) {
                if (lane == 0) {
                    out[j] = ev;
                    atomicAdd(&rowsum[r - r0g], ev);           // LDS atomic
                } else if (lane == 8) {
                    out[NNZ_ + j] = ev;
                    atomicAdd(&segsum[U_NUM_ + c], ev);        // global atomic
                }
            }
        }
    }

    __syncthreads();
    for (int i = tid; i < nrow; i += 256)
        if (rowsum[i] != 0.f) atomicAdd(&segsum[r0g + i], rowsum[i]);
}

// ---------------------------------------------------------------------------
// Pass 2 (R4-proven): normalize by segment sum, coalesced, 4 edges/thread.
// ---------------------------------------------------------------------------
__global__ __launch_bounds__(256) void edge_pass2(
        const int* __restrict__ rows, const int* __restrict__ cols,
        const float* __restrict__ segsum, float* __restrict__ out) {
    int i = blockIdx.x * blockDim.x + threadIdx.x;
    const int stride = gridDim.x * blockDim.x;
    const int n4 = (2 * NNZ_) / 4;
    for (; i < n4; i += stride) {
        float4 v = ((const float4*)out)[i];
        const int base = i * 4;
        int4 seg;
        if (base < NNZ_) {
            seg = *(const int4*)(rows + base);
        } else {
            seg = *(const int4*)(cols + (base - NNZ_));
            seg.x += U_NUM_; seg.y += U_NUM_; seg.z += U_NUM_; seg.w += U_NUM_;
        }
        v.x /= segsum[seg.x];
        v.y /= segsum[seg.y];
        v.z /= segsum[seg.z];
        v.w /= segsum[seg.w];
        ((float4*)out)[i] = v;
    }
}

// ---------------------------------------------------------------------------
// Fallback (round-4 fused kernel) if workspace is too small for the sort.
// ---------------------------------------------------------------------------
__global__ __launch_bounds__(256) void edge_pass1(
        const int* __restrict__ rows, const int* __restrict__ cols,
        const float* __restrict__ u_ui, const float* __restrict__ u_iu,
        const __half* __restrict__ utab, const __half* __restrict__ itab,
        float* __restrict__ out, float* __restrict__ segsum) {
    const int lane = threadIdx.x & 15;
    const int gid  = (blockIdx.x * blockDim.x + threadIdx.x) >> 4;
    const int ngr  = (gridDim.x * blockDim.x) >> 4;
    const uint4* up = (const uint4*)utab;
    const uint4* ip = (const uint4*)itab;
    const bool iu = (lane & 8) != 0;
    const float* unoise = iu ? u_iu : u_ui;
    union H8 { uint4 u; __half2 h[4]; };

    for (int j = gid; j < NNZ_; j += ngr) {
        const int r0 = rows[j], c0 = cols[j];
        H8 a0, b0;
        a0.u = up[(size_t)r0 * 16 + lane];
        b0.u = ip[(size_t)c0 * 16 + lane];
        const float n0 = unoise[j];
        float p0 = 0.f;
        #pragma unroll
        for (int m = 0; m < 4; ++m) {
            float2 x = __half22float2(a0.h[m]), y = __half22float2(b0.h[m]);
            p0 = fmaf(x.x, y.x, p0); p0 = fmaf(x.y, y.y, p0);
        }
        p0 += __shfl_xor(p0, 1);
        p0 += __shfl_xor(p0, 2);
        p0 += __shfl_xor(p0, 4);
        const float e0 = __expf(p0 - __logf(-__logf(n0)));
        if (lane == 0)      { out[j] = e0;        atomicAdd(&segsum[r0], e0); }
        else if (lane == 8) { out[NNZ_ + j] = e0; atomicAdd(&segsum[U_NUM_ + c0], e0); }
    }
}

extern "C" void kernel_launch(void* const* d_in, const int* in_sizes, int n_in,
                              void* d_out, int out_size, void* d_ws, size_t ws_size,
                              hipStream_t stream) {
    const float* user_embed = (const float*)d_in[0];
    const float* item_embed = (const float*)d_in[1];
    const float* Wq = (const float*)d_in[2];
    const float* bq = (const float*)d_in[3];
    const float* Wk = (const float*)d_in[4];
    const float* bk = (const float*)d_in[5];
    const int*   rows = (const int*)d_in[6];
    const int*   cols = (const int*)d_in[7];
    const float* u_ui = (const float*)d_in[8];
    const float* u_iu = (const float*)d_in[9];
    float* out = (float*)d_out;

    const size_t utabB = (size_t)U_NUM_ * 128 * sizeof(__half);   // 12.8 MB
    const size_t itabB = (size_t)I_NUM_ * 128 * sizeof(__half);   // 12.8 MB
    const size_t recB  = (size_t)NNZ_ * 16;                       // 40 MB
    const size_t segB  = (size_t)(U_NUM_ + I_NUM_) * sizeof(float);
    const size_t auxB  = (size_t)(3 * NBKT_ + 1) * sizeof(unsigned);
    const size_t need  = utabB + itabB + recB + segB + auxB;

    __half* utab = (__half*)d_ws;
    __half* itab = (__half*)((char*)d_ws + utabB);

    dim3 pgrid((U_NUM_ + 31) / 32, 4);
    proj_kernel<<<pgrid, 256, 0, stream>>>(user_embed, item_embed, Wq, bq, Wk, bk, utab, itab);

    if (ws_size >= need) {
        char* p = (char*)d_ws + utabB + itabB;
        uint4*    recs    = (uint4*)p;     p += recB;
        float*    segsum  = (float*)p;     p += segB;
        unsigned* gcnt    = (unsigned*)p;  p += NBKT_ * 4;
        unsigned* gbase   = (unsigned*)p;  p += (NBKT_ + 1) * 4;
        unsigned* gcursor = (unsigned*)p;

        hipMemsetAsync(segsum, 0, segB, stream);
        hipMemsetAsync(gcnt, 0, NBKT_ * 4, stream);

        count_kernel<<<1024, 256, 0, stream>>>(rows, gcnt);
        scan_kernel<<<1, 1024, 0, stream>>>(gcnt, gbase, gcursor);
        scatter_kernel<<<1024, 256, 0, stream>>>(rows, cols, u_ui, u_iu, gcursor, recs);
        gather_kernel<<<4 * NBKT_, 256, 0, stream>>>(gbase, recs, utab, itab, out, segsum);
        edge_pass2<<<2048, 256, 0, stream>>>(rows, cols, segsum, out);
    } else {
        float* segsum = (float*)((char*)d_ws + utabB + itabB);
        hipMemsetAsync(segsum, 0, segB, stream);
        edge_pass1<<<4096, 256, 0, stream>>>(rows, cols, u_ui, u_iu, utab, itab, out, segsum);
        edge_pass2<<<2048, 256, 0, stream>>>(rows, cols, segsum, out);
    }
}

// Round 15
// 318.758 us; speedup vs baseline: 1.1070x; 1.1070x over previous
//
#include <hip/hip_runtime.h>
#include <hip/hip_fp16.h>
#include <math.h>

#define U_NUM_ 50000
#define I_NUM_ 50000
#define EMBED_ 64
#define ATT_   64
#define NNZ_   2500000
#define NBKT_  1024
#define BROWS_ 49           // rows per bucket: 1024*49 = 50176 >= 50000

// ---------------------------------------------------------------------------
// REVERT to the round-11 configuration — the best measured (318.8 us total,
// gather 163 us). R12 (record write-back epilogue), R13 (2 blocks/bucket),
// R14 (4 blocks/bucket backfill) all regressed or were neutral: the gather
// is pinned at ~5.5 TB/s aggregate cache-path throughput across occupancy
// 41-72%, MLP 4-8, one-shot/backfilled grids -> hardware ceiling for this
// access shape.
// ---------------------------------------------------------------------------

// ---------------------------------------------------------------------------
// Pass 0: four 50000x64 @ 64x64^T projections, fp32 accumulate, fp16 store,
// interleaved so one row fetch serves both directions:
//   utab[row][  0: 64] = Qu   utab[row][ 64:128] = Ku
//   itab[col][  0: 64] = Ki   itab[col][ 64:128] = Qi
// ---------------------------------------------------------------------------
__global__ __launch_bounds__(256) void proj_kernel(
        const float* __restrict__ user_embed, const float* __restrict__ item_embed,
        const float* __restrict__ Wq, const float* __restrict__ bq,
        const float* __restrict__ Wk, const float* __restrict__ bk,
        __half* __restrict__ utab, __half* __restrict__ itab) {
    __shared__ float Wl[ATT_][EMBED_ + 1];
    __shared__ float El[32][EMBED_];
    __shared__ float bl[ATT_];

    const int combo = blockIdx.y;
    const float* E = (combo == 0 || combo == 3) ? user_embed : item_embed;
    const float* W = (combo == 0 || combo == 2) ? Wq : Wk;
    const float* b = (combo == 0 || combo == 2) ? bq : bk;
    __half* tab    = (combo == 0 || combo == 3) ? utab : itab;
    const int off  = (combo == 0 || combo == 1) ? 0 : 64;

    const int tid = threadIdx.x;

    for (int i4 = tid; i4 < 1024; i4 += 256) {
        const int r = i4 >> 4, c4 = (i4 & 15) * 4;
        float4 w = ((const float4*)W)[i4];
        Wl[r][c4 + 0] = w.x; Wl[r][c4 + 1] = w.y;
        Wl[r][c4 + 2] = w.z; Wl[r][c4 + 3] = w.w;
    }
    if (tid < ATT_) bl[tid] = b[tid];

    const int row0 = blockIdx.x * 32;
    for (int i4 = tid; i4 < 512; i4 += 256) {
        const int r = i4 >> 4, c4 = (i4 & 15) * 4;
        const int gr = row0 + r;
        float4 ev = make_float4(0.f, 0.f, 0.f, 0.f);
        if (gr < U_NUM_) ev = ((const float4*)(E + (size_t)gr * EMBED_))[i4 & 15];
        *(float4*)&El[r][c4] = ev;
    }
    __syncthreads();

    const int a  = tid & 63;
    const int rw = tid >> 6;
    float acc[8];
    #pragma unroll
    for (int k = 0; k < 8; ++k) acc[k] = bl[a];

    #pragma unroll 2
    for (int e4 = 0; e4 < 16; ++e4) {
        const float w0 = Wl[a][e4 * 4 + 0];
        const float w1 = Wl[a][e4 * 4 + 1];
        const float w2 = Wl[a][e4 * 4 + 2];
        const float w3 = Wl[a][e4 * 4 + 3];
        #pragma unroll
        for (int k = 0; k < 8; ++k) {
            float4 ev = *(const float4*)&El[rw + 4 * k][e4 * 4];
            acc[k] = fmaf(ev.x, w0, fmaf(ev.y, w1, fmaf(ev.z, w2, fmaf(ev.w, w3, acc[k]))));
        }
    }

    #pragma unroll
    for (int k = 0; k < 8; ++k) {
        const int gr = row0 + rw + 4 * k;
        if (gr < U_NUM_) tab[(size_t)gr * 128 + off + a] = __float2half(acc[k]);
    }
}

// ---------------------------------------------------------------------------
// Sort 1: per-row-bucket counts (1024 LDS bins, 1024 global atomics / block).
// ---------------------------------------------------------------------------
__global__ __launch_bounds__(256) void count_kernel(
        const int* __restrict__ rows, unsigned* __restrict__ gcnt) {
    __shared__ unsigned cl[NBKT_];
    for (int i = threadIdx.x; i < NBKT_; i += 256) cl[i] = 0;
    __syncthreads();
    int j = blockIdx.x * blockDim.x + threadIdx.x;
    const int st = gridDim.x * blockDim.x;
    for (; j < NNZ_; j += st) atomicAdd(&cl[rows[j] / BROWS_], 1u);
    __syncthreads();
    for (int i = threadIdx.x; i < NBKT_; i += 256)
        if (cl[i]) atomicAdd(&gcnt[i], cl[i]);
}

// ---------------------------------------------------------------------------
// Sort 2: parallel exclusive scan over 1024 counts (Hillis-Steele in LDS).
// ---------------------------------------------------------------------------
__global__ __launch_bounds__(1024) void scan_kernel(
        const unsigned* __restrict__ gcnt,
        unsigned* __restrict__ gbase, unsigned* __restrict__ gcursor) {
    __shared__ unsigned part[NBKT_];
    const int t = threadIdx.x;
    part[t] = gcnt[t];
    __syncthreads();
    #pragma unroll
    for (int off = 1; off < NBKT_; off <<= 1) {
        unsigned v = (t >= off) ? part[t - off] : 0u;
        __syncthreads();
        part[t] += v;
        __syncthreads();
    }
    const unsigned ex = (t == 0) ? 0u : part[t - 1];   // exclusive prefix
    gbase[t] = ex;
    gcursor[t] = ex;
    if (t == NBKT_ - 1) gbase[NBKT_] = part[t];
}

// ---------------------------------------------------------------------------
// Sort 3: scatter edges into bucket-major records. Block reserves per-bucket
// ranges once -> rec writes form contiguous runs.
// Record = {(r<<16)|c, j, u_ui, u_iu}.
// ---------------------------------------------------------------------------
__global__ __launch_bounds__(256) void scatter_kernel(
        const int* __restrict__ rows, const int* __restrict__ cols,
        const float* __restrict__ u_ui, const float* __restrict__ u_iu,
        unsigned* __restrict__ gcursor, uint4* __restrict__ recs) {
    __shared__ unsigned cnt[NBKT_];
    __shared__ unsigned base[NBKT_];
    const int tid = threadIdx.x;
    const int chunk = (NNZ_ + gridDim.x - 1) / gridDim.x;
    const int j0 = blockIdx.x * chunk;
    const int j1 = min(j0 + chunk, NNZ_);
    for (int i = tid; i < NBKT_; i += 256) cnt[i] = 0;
    __syncthreads();
    for (int j = j0 + tid; j < j1; j += 256)
        atomicAdd(&cnt[rows[j] / BROWS_], 1u);
    __syncthreads();
    for (int i = tid; i < NBKT_; i += 256) {
        base[i] = atomicAdd(&gcursor[i], cnt[i]);
        cnt[i] = 0;
    }
    __syncthreads();
    for (int j = j0 + tid; j < j1; j += 256) {
        const int r = rows[j];
        const int b = r / BROWS_;
        const unsigned pos = base[b] + atomicAdd(&cnt[b], 1u);
        uint4 rec;
        rec.x = ((unsigned)r << 16) | (unsigned)cols[j];
        rec.y = (unsigned)j;
        rec.z = __float_as_uint(u_ui[j]);
        rec.w = __float_as_uint(u_iu[j]);
        recs[pos] = rec;
    }
}

// ---------------------------------------------------------------------------
// LDS-staged gather (R11 config): one 512-thread block per bucket.
//  - utab slice (12.25 KB) staged in LDS -> utab off the random path.
//  - 8x unroll: 8 in-flight 16 B itab fetches per thread.
//  - ui row sums accumulate in LDS, flushed with plain stores (atomics
//    halved: cols only; row half of segsum needs no memset).
// Per edge the only random traffic: itab[c] (256 B) + out stores + 1 atomic.
// Max-subtraction skipped (v analytically bounded <= ~31, exp fits f32).
// ---------------------------------------------------------------------------
__global__ __launch_bounds__(512) void gather_kernel(
        const unsigned* __restrict__ gbase, const uint4* __restrict__ recs,
        const __half* __restrict__ utab, const __half* __restrict__ itab,
        float* __restrict__ out, float* __restrict__ segsum) {
    __shared__ uint4 uslice[BROWS_ * 16];            // 49 rows x 256 B = 12544 B
    __shared__ float rowsum[BROWS_];
    const int b    = blockIdx.x;
    const int tid  = threadIdx.x;
    const int lane = tid & 15;
    const int grp  = tid >> 4;                       // 0..31

    const uint4* up = (const uint4*)utab;
    const uint4* ip = (const uint4*)itab;

    const int r0g   = b * BROWS_;
    const int nrow  = max(0, min(BROWS_, U_NUM_ - r0g));
    for (int i = tid; i < nrow * 16; i += 512)
        uslice[i] = up[(size_t)r0g * 16 + i];
    for (int i = tid; i < BROWS_; i += 512) rowsum[i] = 0.f;
    __syncthreads();

    const int s = (int)gbase[b], e = (int)gbase[b + 1];
    const int nq = (e - s + 7) >> 3;
    const bool iu = (lane & 8) != 0;
    union H8 { uint4 u; __half2 h[4]; };

    for (int q = grp; q < nq; q += 32) {
        const int base = s + q * 8;
        const int nv = min(8, e - base);
        uint4 R[8];
        H8 ib[8];
        #pragma unroll
        for (int t = 0; t < 8; ++t) {
            R[t] = recs[(t < nv) ? (base + t) : base];
            ib[t].u = ip[(size_t)(R[t].x & 0xffff) * 16 + lane];  // 8 in flight
        }
        #pragma unroll
        for (int t = 0; t < 8; ++t) {
            H8 ul; ul.u = uslice[((int)(R[t].x >> 16) - r0g) * 16 + lane];
            float p = 0.f;
            #pragma unroll
            for (int m = 0; m < 4; ++m) {
                float2 x = __half22float2(ul.h[m]);
                float2 y = __half22float2(ib[t].h[m]);
                p = fmaf(x.x, y.x, p); p = fmaf(x.y, y.y, p);
            }
            p += __shfl_xor(p, 1);
            p += __shfl_xor(p, 2);
            p += __shfl_xor(p, 4);
            const float n  = __uint_as_float(iu ? R[t].w : R[t].z);
            const float ev = __expf(p - __logf(-__logf(n)));   // TAU = 1
            const int r = (int)(R[t].x >> 16), c = (int)(R[t].x & 0xffff);
            const int j = (int)R[t].y;
            if (t < nv) {
                if (lane == 0) {
                    out[j] = ev;
                    atomicAdd(&rowsum[r - r0g], ev);           // LDS atomic
                } else if (lane == 8) {
                    out[NNZ_ + j] = ev;
                    atomicAdd(&segsum[U_NUM_ + c], ev);        // global atomic
                }
            }
        }
    }

    __syncthreads();
    for (int i = tid; i < nrow; i += 512)
        segsum[r0g + i] = rowsum[i];                 // plain store: rows disjoint
}

// ---------------------------------------------------------------------------
// Pass 2 (R4-proven): normalize by segment sum, coalesced, 4 edges/thread.
// ---------------------------------------------------------------------------
__global__ __launch_bounds__(256) void edge_pass2(
        const int* __restrict__ rows, const int* __restrict__ cols,
        const float* __restrict__ segsum, float* __restrict__ out) {
    int i = blockIdx.x * blockDim.x + threadIdx.x;
    const int stride = gridDim.x * blockDim.x;
    const int n4 = (2 * NNZ_) / 4;
    for (; i < n4; i += stride) {
        float4 v = ((const float4*)out)[i];
        const int base = i * 4;
        int4 seg;
        if (base < NNZ_) {
            seg = *(const int4*)(rows + base);
        } else {
            seg = *(const int4*)(cols + (base - NNZ_));
            seg.x += U_NUM_; seg.y += U_NUM_; seg.z += U_NUM_; seg.w += U_NUM_;
        }
        v.x /= segsum[seg.x];
        v.y /= segsum[seg.y];
        v.z /= segsum[seg.z];
        v.w /= segsum[seg.w];
        ((float4*)out)[i] = v;
    }
}

// ---------------------------------------------------------------------------
// Fallback (round-4 fused kernel) if workspace is too small for the sort.
// ---------------------------------------------------------------------------
__global__ __launch_bounds__(256) void edge_pass1(
        const int* __restrict__ rows, const int* __restrict__ cols,
        const float* __restrict__ u_ui, const float* __restrict__ u_iu,
        const __half* __restrict__ utab, const __half* __restrict__ itab,
        float* __restrict__ out, float* __restrict__ segsum) {
    const int lane = threadIdx.x & 15;
    const int gid  = (blockIdx.x * blockDim.x + threadIdx.x) >> 4;
    const int ngr  = (gridDim.x * blockDim.x) >> 4;
    const uint4* up = (const uint4*)utab;
    const uint4* ip = (const uint4*)itab;
    const bool iu = (lane & 8) != 0;
    const float* unoise = iu ? u_iu : u_ui;
    union H8 { uint4 u; __half2 h[4]; };

    for (int j = gid; j < NNZ_; j += ngr) {
        const int r0 = rows[j], c0 = cols[j];
        H8 a0, b0;
        a0.u = up[(size_t)r0 * 16 + lane];
        b0.u = ip[(size_t)c0 * 16 + lane];
        const float n0 = unoise[j];
        float p0 = 0.f;
        #pragma unroll
        for (int m = 0; m < 4; ++m) {
            float2 x = __half22float2(a0.h[m]), y = __half22float2(b0.h[m]);
            p0 = fmaf(x.x, y.x, p0); p0 = fmaf(x.y, y.y, p0);
        }
        p0 += __shfl_xor(p0, 1);
        p0 += __shfl_xor(p0, 2);
        p0 += __shfl_xor(p0, 4);
        const float e0 = __expf(p0 - __logf(-__logf(n0)));
        if (lane == 0)      { out[j] = e0;        atomicAdd(&segsum[r0], e0); }
        else if (lane == 8) { out[NNZ_ + j] = e0; atomicAdd(&segsum[U_NUM_ + c0], e0); }
    }
}

extern "C" void kernel_launch(void* const* d_in, const int* in_sizes, int n_in,
                              void* d_out, int out_size, void* d_ws, size_t ws_size,
                              hipStream_t stream) {
    const float* user_embed = (const float*)d_in[0];
    const float* item_embed = (const float*)d_in[1];
    const float* Wq = (const float*)d_in[2];
    const float* bq = (const float*)d_in[3];
    const float* Wk = (const float*)d_in[4];
    const float* bk = (const float*)d_in[5];
    const int*   rows = (const int*)d_in[6];
    const int*   cols = (const int*)d_in[7];
    const float* u_ui = (const float*)d_in[8];
    const float* u_iu = (const float*)d_in[9];
    float* out = (float*)d_out;

    const size_t utabB = (size_t)U_NUM_ * 128 * sizeof(__half);   // 12.8 MB
    const size_t itabB = (size_t)I_NUM_ * 128 * sizeof(__half);   // 12.8 MB
    const size_t recB  = (size_t)NNZ_ * 16;                       // 40 MB
    const size_t segB  = (size_t)(U_NUM_ + I_NUM_) * sizeof(float);
    const size_t auxB  = (size_t)(3 * NBKT_ + 1) * sizeof(unsigned);
    const size_t need  = utabB + itabB + recB + segB + auxB;

    __half* utab = (__half*)d_ws;
    __half* itab = (__half*)((char*)d_ws + utabB);

    dim3 pgrid((U_NUM_ + 31) / 32, 4);
    proj_kernel<<<pgrid, 256, 0, stream>>>(user_embed, item_embed, Wq, bq, Wk, bk, utab, itab);

    if (ws_size >= need) {
        char* p = (char*)d_ws + utabB + itabB;
        uint4*    recs    = (uint4*)p;     p += recB;
        float*    segsum  = (float*)p;     p += segB;
        unsigned* gcnt    = (unsigned*)p;  p += NBKT_ * 4;
        unsigned* gbase   = (unsigned*)p;  p += (NBKT_ + 1) * 4;
        unsigned* gcursor = (unsigned*)p;

        // only the COLUMN half of segsum is atomically accumulated
        hipMemsetAsync(segsum + U_NUM_, 0, (size_t)I_NUM_ * sizeof(float), stream);
        hipMemsetAsync(gcnt, 0, NBKT_ * 4, stream);

        count_kernel<<<1024, 256, 0, stream>>>(rows, gcnt);
        scan_kernel<<<1, 1024, 0, stream>>>(gcnt, gbase, gcursor);
        scatter_kernel<<<512, 256, 0, stream>>>(rows, cols, u_ui, u_iu, gcursor, recs);
        gather_kernel<<<NBKT_, 512, 0, stream>>>(gbase, recs, utab, itab, out, segsum);
        edge_pass2<<<2048, 256, 0, stream>>>(rows, cols, segsum, out);
    } else {
        float* segsum = (float*)((char*)d_ws + utabB + itabB);
        hipMemsetAsync(segsum, 0, segB, stream);
        edge_pass1<<<4096, 256, 0, stream>>>(rows, cols, u_ui, u_iu, utab, itab, out, segsum);
        edge_pass2<<<2048, 256, 0, stream>>>(rows, cols, segsum, out);
    }
}